// Round 17
// baseline (68.141 us; speedup 1.0000x reference)
//
#include <hip/hip_runtime.h>
#include <stdint.h>

// DeformConv1d: x[8,256,4096] f32, offsets[8,1,4094,3] f32,
// weight[256,256,3] f32, bias[256] f32 -> out[8,256,4094] f32.
//
// R17: occupancy via finer t-split, no register holding.
//  - BN 64 -> 32, grid 1024 (4 blocks/CU by LDS; ~3 by VGPR) vs grid-capped
//    2 before. Nothing duplicated per-t except 4 window edge positions.
//  - launch_bounds(512,6): VGPR cap ~80, no spill (R15/R16 spilled by
//    holding staging regs across GEMM; acc shares the unified file).
//  - Burst staging (issue 3 float4 groups, drain 3) - regs live briefly.
//  - wave = 32 rows x 32 t: acc = 16 f32; Bp tile 32t x 128c (8KB).
// Unchanged: 32x32x16 MFMA, wave-private A from L2 + prefetch, swizzled
// Xt/Bp, register meta, LDS epilogue, XCD-chunked decode.

constexpr int CIN  = 256;
constexpr int LX   = 4096;
constexpr int KT   = 3;
constexpr int OUTL = 4094;
constexpr int COUT = 256;
constexpr int BN   = 32;    // t per block
constexpr int WPOS = 36;    // window positions staged (t0 .. t0+35)
constexpr int NQ   = 24;    // K-chunks of 32
constexpr int EPIW = 36;    // padded epilogue row (floats)
constexpr int NIT  = 1152;  // 128 c * 9 float4-groups

typedef __attribute__((ext_vector_type(8))) short bf16x8;
typedef __attribute__((ext_vector_type(4))) float f32x4;
typedef __attribute__((ext_vector_type(16))) float f32x16;

__device__ __forceinline__ short f2bf(float f) {        // round-half-up
  union { float f; uint32_t u; } v; v.f = f;
  return (short)((v.u + 0x8000u) >> 16);
}
__device__ __forceinline__ float bf2f(short s) {
  union { uint32_t u; float f; } v;
  v.u = ((uint32_t)(uint16_t)s) << 16;
  return v.f;
}
__device__ __forceinline__ float4 loadx4(const float* p, int l) {
  if (l + 3 < LX) return *(const float4*)(p + l);   // l is 16B-aligned
  float4 v; v.x = v.y = v.z = v.w = 0.f;
  if (l + 0 < LX) v.x = p[l + 0];
  if (l + 1 < LX) v.y = p[l + 1];
  if (l + 2 < LX) v.z = p[l + 2];
  return v;
}

// A pack (same as R14/R15): shorts idx = ((q*2+h)*8 + mf)*512 + l*8 + j
//   row = mf*32 + (l&31); c = ch*128 + (ks&3)*32 + h*16 + (l>>5)*8 + j;
//   tap = (q%12)>>2.  Wave mf's K16-slice (q,h) = ONE coalesced 1KB load.
__global__ __launch_bounds__(256) void pack_weights_kernel(
    const float* __restrict__ w, short* __restrict__ ap) {
  const int gid = blockIdx.x * 256 + threadIdx.x;
  if (gid >= NQ * 2 * 8 * 64) return;
  const int l   = gid & 63;
  const int mf  = (gid >> 6) & 7;
  const int h   = (gid >> 9) & 1;
  const int q   = gid >> 10;
  const int ch  = q / 12;
  const int ks  = q % 12;
  const int tap = ks >> 2;
  const int c0  = ch * 128 + (ks & 3) * 32 + h * 16 + (l >> 5) * 8;
  const int row = mf * 32 + (l & 31);
  bf16x8 v;
  #pragma unroll
  for (int j = 0; j < 8; ++j) {
    v[j] = f2bf(w[((size_t)row * CIN + c0 + j) * KT + tap]);
  }
  *(bf16x8*)(ap + (size_t)gid * 8) = v;
}

__global__ __launch_bounds__(512, 6) void deform_gemm_kernel(
    const float* __restrict__ x, const float* __restrict__ off,
    const short* __restrict__ ap, const float* __restrict__ bias,
    float* __restrict__ out) {

  // arena: [0,9216) Xt (36x128 bf16) / Epi (64x36 f32, reuse),
  //        [9216,17408) Bp (32x128 bf16), [17408,18432) biasS. 18.4 KB.
  __shared__ __align__(16) char smem[9216 + 8192 + 1024];
  short* Xt    = (short*)smem;
  short* Bp    = (short*)(smem + 9216);
  float* Epi   = (float*)smem;          // needs 64*36*4 = 9216 B: exact
  float* biasS = (float*)(smem + 9216 + 8192);

  const int tid  = threadIdx.x;
  const int lane = tid & 63;
  const int wid  = tid >> 6;       // 0..7 = M-frag index (rows wid*32..)
  const int l31  = lane & 31;
  const int lh   = lane >> 5;      // k-half within fragment

  // decode: b in low 3 bits (XCD-chunk: whole batch on one XCD)
  const int b  = blockIdx.x & 7;    // 8 batches
  const int tt = blockIdx.x >> 3;   // 128 t-tiles
  const int t0 = tt * BN;

  // ---- per-thread interp meta (t = t0 + (tid&31)) ----
  float w0m[3], w1m[3];
  int   d0m[3];
  {
    const int t = t0 + (tid & 31);
    #pragma unroll
    for (int k = 0; k < KT; ++k) {
      float w0 = 0.f, w1 = 0.f; int d0 = 0;
      if (t < OUTL) {
        const float o = off[((size_t)b * OUTL + t) * KT + k];
        float T = (float)(t + k) + o;
        T = fminf(fmaxf(T, (float)t), (float)(t + 2));  // clip to [t, t+2]
        int U0 = (int)T;                                 // floor (T >= 0)
        if (U0 > LX - 2) U0 = LX - 2;
        w1 = T - (float)U0;                              // in [0,1]
        w0 = 1.f - w1;
        d0 = U0 - t0;                                    // in [0, 33]
      }
      w0m[k] = w0; w1m[k] = w1; d0m[k] = d0;
    }
  }
  if (tid < COUT) biasS[tid] = bias[tid];

  f32x16 acc = {0.f,0.f,0.f,0.f,0.f,0.f,0.f,0.f,0.f,0.f,0.f,0.f,0.f,0.f,0.f,0.f};

  const float* xb = x + (size_t)b * CIN * LX;

  // A: wave-private coalesced loads; preload step 0 (both K16 halves)
  const short* apw = ap + wid * 512 + lane * 8;
  bf16x8 aC0 = *(const bf16x8*)apw;
  bf16x8 aC1 = *(const bf16x8*)(apw + 4096);

  #pragma unroll 1
  for (int ch = 0; ch < 2; ++ch) {            // c-halves (ROLLED)
    if (ch) __syncthreads();                  // prev half's Xt readers done
    // ---- stage x window half: burst issue then drain (3-deep MLP) ----
    {
      float4 xv[3];
      #pragma unroll
      for (int r = 0; r < 3; ++r) {
        const int idx = r * 512 + tid;
        if (idx < NIT) {
          const int c = idx / 9, g = idx - c * 9;
          xv[r] = loadx4(xb + (size_t)(ch * 128 + c) * LX, t0 + 4 * g);
        }
      }
      #pragma unroll
      for (int r = 0; r < 3; ++r) {
        const int idx = r * 512 + tid;
        if (idx < NIT) {
          const int c = idx / 9, g = idx - c * 9;
          const float fe[4] = {xv[r].x, xv[r].y, xv[r].z, xv[r].w};
          #pragma unroll
          for (int e = 0; e < 4; ++e) {
            const int pos = g * 4 + e;
            Xt[(pos * 128 + c) ^ ((pos & 7) << 3)] = f2bf(fe[e]);
          }
        }
      }
    }
    __syncthreads();  // window (and bias on first pass) visible

    #pragma unroll
    for (int tap = 0; tap < KT; ++tap) {      // UNROLLED: static meta index
      if (tap) __syncthreads();               // drain prev tap's Bp readers

      // ---- build Bp[t][c] (swizzled): 32t x 128c, 1 write/thread ----
      {
        const int tq = tid & 31;              // t
        const int c0 = (tid >> 5) * 8;        // c-granule (0..120)
        const float w0 = w0m[tap], w1 = w1m[tap];
        const int   d0 = d0m[tap];
        const int sw0 = (d0 & 7) << 3;
        const int sw1 = ((d0 + 1) & 7) << 3;
        const bf16x8 r0 = *(const bf16x8*)&Xt[(d0 * 128 + c0)       ^ sw0];
        const bf16x8 r1 = *(const bf16x8*)&Xt[((d0 + 1) * 128 + c0) ^ sw1];
        bf16x8 o;
        #pragma unroll
        for (int j = 0; j < 8; ++j)
          o[j] = f2bf(bf2f(r0[j]) * w0 + bf2f(r1[j]) * w1);
        *(bf16x8*)&Bp[(tq * 128 + c0) ^ ((tq & 7) << 3)] = o;
      }
      __syncthreads();  // Bp ready

      // ---- 4 barrier-free K-steps (K=32 each) ----
      #pragma unroll 1
      for (int csub = 0; csub < 4; ++csub) {
        const int q  = ch * 12 + tap * 4 + csub;
        const int qn = q < NQ - 1 ? q + 1 : NQ - 1;
        // prefetch next step's A (wave-private, L2-hot)
        const bf16x8 aN0 = *(const bf16x8*)(apw + (size_t)qn * 8192);
        const bf16x8 aN1 = *(const bf16x8*)(apw + (size_t)qn * 8192 + 4096);

        // B-frags: lane = col t' = l31; elem j -> c = csub*32 + lh*8 + j (+16)
        const int cbase = csub * 32 + lh * 8;
        const int swt   = (l31 & 7) << 3;
        const bf16x8 b0 = *(const bf16x8*)&Bp[(l31 * 128 + cbase)      ^ swt];
        const bf16x8 b1 = *(const bf16x8*)&Bp[(l31 * 128 + cbase + 16) ^ swt];

        acc = __builtin_amdgcn_mfma_f32_32x32x16_bf16(aC0, b0, acc, 0, 0, 0);
        acc = __builtin_amdgcn_mfma_f32_32x32x16_bf16(aC1, b1, acc, 0, 0, 0);

        aC0 = aN0; aC1 = aN1;
      }
    }
  }

  // ---- epilogue: LDS-staged, contiguous row-segment stores ----
  // 4 passes of 64 rows; producers = waves 2p, 2p+1 (their own M-frags).
  // 32x32 C/D layout: col = lane&31, row = (r&3) + 8*(r>>2) + 4*(lane>>5).
  const size_t obase = (size_t)b * COUT * OUTL;
  #pragma unroll
  for (int p = 0; p < 4; ++p) {
    __syncthreads();   // p==0: Xt->Epi reuse safe; else: prev consume done
    if ((wid >> 1) == p) {
      const int lrb = (wid & 1) * 32;
      #pragma unroll
      for (int r = 0; r < 16; ++r) {
        const int rowl = (r & 3) + 8 * (r >> 2) + 4 * lh;   // 0..31
        Epi[(lrb + rowl) * EPIW + l31] = acc[r] + biasS[wid * 32 + rowl];
      }
    }
    __syncthreads();
    // consumer: 512 threads, 64 rows x 32 t f32 tile; 16B per thread
    const int rr = tid >> 3;               // 0..63
    const int c4 = (tid & 7) * 4;          // 0..28
    const f32x4 v = *(const f32x4*)&Epi[rr * EPIW + c4];
    const int   t = t0 + c4;
    float* op = out + obase + (size_t)(p * 64 + rr) * OUTL + t;
    if (t + 3 < OUTL) {
      *(f32x4*)op = v;
    } else {
      #pragma unroll
      for (int e = 0; e < 4; ++e)
        if (t + e < OUTL) op[e] = v[e];
    }
  }
}

extern "C" void kernel_launch(void* const* d_in, const int* in_sizes, int n_in,
                              void* d_out, int out_size, void* d_ws, size_t ws_size,
                              hipStream_t stream) {
  const float* x    = (const float*)d_in[0];
  const float* off  = (const float*)d_in[1];
  const float* wgt  = (const float*)d_in[2];
  const float* bias = (const float*)d_in[3];
  float* out  = (float*)d_out;
  short* ap   = (short*)d_ws;   // 24*2*8*64*8 shorts = 393216 B of scratch

  // pack weights into wave-private coalesced A layout (~3 us)
  pack_weights_kernel<<<dim3(NQ * 2 * 8 * 64 / 256), dim3(256), 0, stream>>>(wgt, ap);
  // 8 b x 128 tt = 1024 blocks (3-4/CU), 512 threads (8 waves)
  deform_gemm_kernel<<<dim3(1024), dim3(512), 0, stream>>>(x, off, ap, bias, out);
}